// Round 6
// baseline (466.639 us; speedup 1.0000x reference)
//
#include <hip/hip_runtime.h>
#include <hip/hip_fp16.h>
#include <math.h>

typedef _Float16 half8  __attribute__((ext_vector_type(8)));
typedef _Float16 half4v __attribute__((ext_vector_type(4)));
typedef float    f32x4  __attribute__((ext_vector_type(4)));

#define MFMA_F16 __builtin_amdgcn_mfma_f32_16x16x32_f16

namespace {

constexpr int M_ROWS = 64;                   // rows per block (4 waves x 64x64 tile)
// XOR-swizzled packed layouts (granule = 8 halves = 16 B):
//   Haddr(m,n) = m*256 + (((n>>3) ^ (m&7))<<3) + (n&7)     H: 64x256 = 32 KB
//   Paddr(m,k) = PE_OFF + m*64 + (((k>>3) ^ (m&7))<<3) + (k&7)   PE: 8 KB
// 40 KB/block -> up to 4 blocks/CU by LDS.
constexpr int H_OFF      = 0;
constexpr int PE_OFF     = M_ROWS * 256;          // 16384 halves
constexpr int LDS_HALVES = PE_OFF + M_ROWS * 64;  // 20480 halves = 40960 B
constexpr size_t LDS_BYTES = (size_t)LDS_HALVES * sizeof(_Float16);

// Layer order: g1_0..g1_4, g2_0..g2_2, c_0, c_1, sig
constexpr int KCH_A[11] = {2,8,8,8,8,10,8,8,10,8,8};
constexpr int OFF_A[11] = {0,16384,81920,147456,212992,278528,360448,425984,491520,573440,577536};
constexpr int TOTAL_W   = 581632;   // fp16 elements in swizzled blob

struct Ptr11 { const float* p[11]; };

// ---------------------------------------------------------------------------
// Weight pre-swizzle (unchanged since R2): A-fragment layout for
// mfma_f32_16x16x32_f16: blob[(nt*KCH + kc)*512 + lane*8 + j] =
//   W[remap(kc*32 + (lane>>4)*8 + j)][nt*16 + (lane&15)]  as fp16, 0 if padded.
// ---------------------------------------------------------------------------
__global__ void prep_kernel(Ptr11 wp, _Float16* __restrict__ ws) {
  int tid = blockIdx.x * blockDim.x + threadIdx.x;
  if (tid >= TOTAL_W) return;
  int L = 0;
#pragma unroll
  for (int i = 1; i < 11; ++i) if (tid >= OFF_A[i]) L = i;
  int e    = tid - OFF_A[L];
  int j    = e & 7;
  int lane = (e >> 3) & 63;
  int blk  = e >> 9;
  int kch  = KCH_A[L];
  int kc   = blk % kch;
  int kpad = kc * 32 + ((lane >> 4) << 3) + j;
  int n    = ((blk / kch) << 4) + (lane & 15);
  int k;
  if      (L == 0) k = (kpad < 63) ? kpad : -1;                               // g1_0: din 63 pad->64
  else if (L == 5) k = (kpad < 64) ? ((kpad < 63) ? kpad : -1) : kpad - 1;    // g2_0: [pe_x 63|f1 256]
  else if (L == 8) k = (kpad < 64) ? ((kpad < 39) ? kpad : -1) : kpad - 25;   // c_0:  [pe_d 39|f2 256]
  else             k = kpad;                                                  // din 256 exact
  int dout = (L == 9) ? 3 : ((L == 10) ? 1 : 256);
  float v = 0.f;
  if (k >= 0 && n < dout) v = wp.p[L][k * dout + n];
  ws[tid] = (_Float16)v;
}

// ---------------------------------------------------------------------------
// One 256-out linear layer; wave cg (0..3) computes the 64x64 tile
// rows [0,64) x cols [cg*64, cg*64+64).
// R5 lesson: the rolled `unroll 2` K-loop re-computes 8 load addresses per
// iteration -> VALUBusy 45% > MfmaUtil 37%. Full unroll turns addresses into
// immediate offsets + lets the scheduler pipeline loads deep. R4 lesson: full
// unroll spills only when the VGPR cap < ~180 -> keep cap at 256 via (256,2).
// ---------------------------------------------------------------------------
template <int PE_CH, int H_CH, bool RELU>
__device__ __forceinline__ void do_layer(_Float16* lds,
                                         const _Float16* __restrict__ blob,
                                         const float* __restrict__ bias,
                                         int cg, int lane) {
  constexpr int KCH = PE_CH + H_CH;
  const int l15  = lane & 15;
  const int quad = lane >> 4;
  const int s7   = l15 & 7;          // swizzle key (row&7 == l15&7, rows = mt*16+l15)

  f32x4 acc[4][4];
#pragma unroll
  for (int mt = 0; mt < 4; ++mt)
#pragma unroll
    for (int nt = 0; nt < 4; ++nt) acc[mt][nt] = (f32x4)0.f;

  half8 a[4], b[4];

  // ---- PE segment (<=2 chunks, fully unrolled) ----
#pragma unroll
  for (int kcg = 0; kcg < PE_CH; ++kcg) {
#pragma unroll
    for (int nt = 0; nt < 4; ++nt)
      a[nt] = *(const half8*)(blob + ((((cg * 4 + nt) * KCH) + kcg) * 64 + lane) * 8);
    const int xg = ((kcg * 4 + quad) ^ s7) << 3;
#pragma unroll
    for (int mt = 0; mt < 4; ++mt)
      b[mt] = *(const half8*)(lds + PE_OFF + (mt * 16 + l15) * 64 + xg);
#pragma unroll
    for (int mt = 0; mt < 4; ++mt)
#pragma unroll
      for (int nt = 0; nt < 4; ++nt)
        acc[mt][nt] = MFMA_F16(a[nt], b[mt], acc[mt][nt], 0, 0, 0);
  }

  // ---- H segment (fully unrolled; cap-256 keeps it spill-free) ----
#pragma unroll
  for (int kcg = PE_CH; kcg < KCH; ++kcg) {
#pragma unroll
    for (int nt = 0; nt < 4; ++nt)
      a[nt] = *(const half8*)(blob + ((((cg * 4 + nt) * KCH) + kcg) * 64 + lane) * 8);
    const int xg = (((kcg - PE_CH) * 4 + quad) ^ s7) << 3;
#pragma unroll
    for (int mt = 0; mt < 4; ++mt)
      b[mt] = *(const half8*)(lds + H_OFF + (mt * 16 + l15) * 256 + xg);
#pragma unroll
    for (int mt = 0; mt < 4; ++mt)
#pragma unroll
      for (int nt = 0; nt < 4; ++nt)
        acc[mt][nt] = MFMA_F16(a[nt], b[mt], acc[mt][nt], 0, 0, 0);
  }

  __syncthreads();   // all waves done READING H/PE before anyone overwrites H
#pragma unroll
  for (int mt = 0; mt < 4; ++mt) {
    int m = mt * 16 + l15;
#pragma unroll
    for (int nt = 0; nt < 4; ++nt) {
      int n0 = cg * 64 + nt * 16 + quad * 4;
      f32x4 v = acc[mt][nt];
      f32x4 bb = *(const f32x4*)(bias + n0);
      v += bb;
      if (RELU) {
        v.x = fmaxf(v.x, 0.f); v.y = fmaxf(v.y, 0.f);
        v.z = fmaxf(v.z, 0.f); v.w = fmaxf(v.w, 0.f);
      }
      half4v hv = { (_Float16)v.x, (_Float16)v.y, (_Float16)v.z, (_Float16)v.w };
      // granule of n0 = cg*8 + nt*2 + (quad>>1); in-granule offset (quad&1)*4
      int wa = m * 256 + ((((cg * 8 + nt * 2 + (quad >> 1)) ^ s7)) << 3) +
               ((quad & 1) << 2);
      *(half4v*)(lds + H_OFF + wa) = hv;
    }
  }
  __syncthreads();
}

// Head (sig / c_1): NT=1 blob, K=256 over H; wave w covers rows [w*16,w*16+16).
__device__ __forceinline__ f32x4 head_mt(const _Float16* lds,
                                         const _Float16* __restrict__ blob,
                                         int w, int lane) {
  const int l15  = lane & 15;
  const int quad = lane >> 4;
  const int s7   = l15 & 7;
  f32x4 res = (f32x4)0.f;
#pragma unroll
  for (int kc = 0; kc < 8; ++kc) {
    half8 a = *(const half8*)(blob + (kc * 64 + lane) * 8);
    half8 b = *(const half8*)(lds + H_OFF + (w * 16 + l15) * 256 +
                              (((kc * 4 + quad) ^ s7) << 3));
    res = MFMA_F16(a, b, res, 0, 0, 0);
  }
  return res;
}

// Positional-encoding pass: NFEAT real features (63 or 39) into PE buffer.
__device__ __forceinline__ void pe_pass(_Float16* lds, const float* __restrict__ src,
                                        int row0, int tid, int nfeat) {
  for (int i = tid; i < M_ROWS * 64; i += 256) {
    int r = i >> 6, f = i & 63;
    float v = 0.f;
    if (f < 3) {
      v = src[(row0 + r) * 3 + f];
    } else if (f < nfeat) {
      int g = f - 3, li = g / 6, rem = g % 6, sc = rem / 3, c = rem % 3;
      float a = src[(row0 + r) * 3 + c] * (float)(1 << li);
      v = sc ? cosf(a) : sinf(a);
    }
    lds[PE_OFF + r * 64 + (((f >> 3) ^ (r & 7)) << 3) + (f & 7)] = (_Float16)v;
  }
}

__global__ __launch_bounds__(256, 2) void nerf_kernel(
    const _Float16* __restrict__ ws, const float* __restrict__ x,
    const float* __restrict__ dirp, Ptr11 bp, float* __restrict__ out) {
  extern __shared__ _Float16 lds[];
  const int tid  = threadIdx.x;
  const int lane = tid & 63;
  const int w    = tid >> 6;       // wave 0..3 (= col-group cg)
  const int l15  = lane & 15;
  const int quad = lane >> 4;
  const int row0 = blockIdx.x * M_ROWS;

  // ---- pe_x -> PE buffer ----
  pe_pass(lds, x, row0, tid, 63);
  __syncthreads();

  // ---- G1: 63->256, 256->256 x4 (ReLU on all but last) ----
  do_layer<2, 0, true >(lds, ws + OFF_A[0], bp.p[0], w, lane);
  do_layer<0, 8, true >(lds, ws + OFF_A[1], bp.p[1], w, lane);
  do_layer<0, 8, true >(lds, ws + OFF_A[2], bp.p[2], w, lane);
  do_layer<0, 8, true >(lds, ws + OFF_A[3], bp.p[3], w, lane);
  do_layer<0, 8, false>(lds, ws + OFF_A[4], bp.p[4], w, lane);  // f1
  // ---- G2: [pe_x|f1] -> 256, 256->256, 256->256 (no ReLU on last) ----
  do_layer<2, 8, true >(lds, ws + OFF_A[5], bp.p[5], w, lane);  // pe_x last use
  do_layer<0, 8, true >(lds, ws + OFF_A[6], bp.p[6], w, lane);
  do_layer<0, 8, false>(lds, ws + OFF_A[7], bp.p[7], w, lane);  // f2

  // ---- sigma head: wave w covers rows [w*16, w*16+16) (reads f2 in H) ----
  f32x4 sa = head_mt(lds, ws + OFF_A[10], w, lane);
  float sigv = sa[0] + bp.p[10][0];   // valid in quad==0 lanes

  // ---- pe_d recompute into PE buffer (pe_x dead after g2_0) ----
  pe_pass(lds, dirp, row0, tid, 39);
  __syncthreads();   // PE writes visible; sig reads done (barrier covers both)

  // ---- color: [pe_d|f2] -> 256 (ReLU), then 256 -> 3 ----
  do_layer<2, 8, true>(lds, ws + OFF_A[8], bp.p[8], w, lane);
  f32x4 ca = head_mt(lds, ws + OFF_A[9], w, lane);
  if (quad == 0) {
    f32x4 o = { ca[0] + bp.p[9][0], ca[1] + bp.p[9][1], ca[2] + bp.p[9][2], sigv };
    *(f32x4*)(out + (size_t)(row0 + w * 16 + l15) * 4) = o;
  }
}

}  // namespace

extern "C" void kernel_launch(void* const* d_in, const int* in_sizes, int n_in,
                              void* d_out, int out_size, void* d_ws, size_t ws_size,
                              hipStream_t stream) {
  const float* x   = (const float*)d_in[0];
  const float* dir = (const float*)d_in[1];
  Ptr11 wp, bp;
  for (int i = 0; i < 11; ++i) {
    wp.p[i] = (const float*)d_in[2 + 2 * i];
    bp.p[i] = (const float*)d_in[3 + 2 * i];
  }
  _Float16* ws = (_Float16*)d_ws;
  float* out = (float*)d_out;

  hipFuncSetAttribute((const void*)nerf_kernel,
                      hipFuncAttributeMaxDynamicSharedMemorySize, (int)LDS_BYTES);

  prep_kernel<<<TOTAL_W / 256, 256, 0, stream>>>(wp, ws);
  nerf_kernel<<<262144 / M_ROWS, 256, LDS_BYTES, stream>>>(ws, x, dir, bp, out);
}

// Round 7
// 442.655 us; speedup vs baseline: 1.0542x; 1.0542x over previous
//
#include <hip/hip_runtime.h>
#include <hip/hip_fp16.h>
#include <math.h>

typedef _Float16 half8  __attribute__((ext_vector_type(8)));
typedef _Float16 half4v __attribute__((ext_vector_type(4)));
typedef float    f32x4  __attribute__((ext_vector_type(4)));

#define MFMA_F16 __builtin_amdgcn_mfma_f32_16x16x32_f16

namespace {

constexpr int M_ROWS = 64;                   // rows per block (4 waves x 64x64 tile)
// XOR-swizzled packed layouts (granule = 8 halves = 16 B):
//   Haddr(m,n) = m*256 + (((n>>3) ^ (m&7))<<3) + (n&7)     H: 64x256 = 32 KB
//   Paddr(m,k) = PE_OFF + m*64 + (((k>>3) ^ (m&7))<<3) + (k&7)   PE: 8 KB
// 40 KB/block. Occupancy model (R2/R5/R6): waves/SIMD = 512/(VGPR+64 AGPR);
// keep VGPR <= ~106 for 3 waves/SIMD.
constexpr int H_OFF      = 0;
constexpr int PE_OFF     = M_ROWS * 256;          // 16384 halves
constexpr int LDS_HALVES = PE_OFF + M_ROWS * 64;  // 20480 halves = 40960 B
constexpr size_t LDS_BYTES = (size_t)LDS_HALVES * sizeof(_Float16);

// Layer order: g1_0..g1_4, g2_0..g2_2, c_0, c_1, sig
constexpr int KCH_A[11] = {2,8,8,8,8,10,8,8,10,8,8};
constexpr int OFF_A[11] = {0,16384,81920,147456,212992,278528,360448,425984,491520,573440,577536};
constexpr int TOTAL_W   = 581632;   // fp16 elements in swizzled blob

struct Ptr11 { const float* p[11]; };

// ---------------------------------------------------------------------------
// Weight pre-swizzle. NEW layout (R7): ntile innermost so the K-loop's 4
// a-loads share one pointer with 1024 B immediate offsets:
//   256-out layers: blob[((kc*16 + ntile)*64 + lane)*8 + j]
//   heads (L=9,10): blob[(kc*64 + lane)*8 + j]
// Fragment semantics unchanged: W[remap(kc*32 + (lane>>4)*8 + j)][ntile*16 +
// (lane&15)] as fp16, 0 if padded (A-frag for mfma_f32_16x16x32_f16).
// ---------------------------------------------------------------------------
__global__ void prep_kernel(Ptr11 wp, _Float16* __restrict__ ws) {
  int tid = blockIdx.x * blockDim.x + threadIdx.x;
  if (tid >= TOTAL_W) return;
  int L = 0;
#pragma unroll
  for (int i = 1; i < 11; ++i) if (tid >= OFF_A[i]) L = i;
  int e    = tid - OFF_A[L];
  int j    = e & 7;
  int lane = (e >> 3) & 63;
  int blk  = e >> 9;
  int kc, nt;
  if (L <= 8) { kc = blk >> 4; nt = blk & 15; }
  else        { kc = blk;      nt = 0; }
  int kpad = kc * 32 + ((lane >> 4) << 3) + j;
  int n    = nt * 16 + (lane & 15);
  int k;
  if      (L == 0) k = (kpad < 63) ? kpad : -1;                               // g1_0: din 63 pad->64
  else if (L == 5) k = (kpad < 64) ? ((kpad < 63) ? kpad : -1) : kpad - 1;    // g2_0: [pe_x 63|f1 256]
  else if (L == 8) k = (kpad < 64) ? ((kpad < 39) ? kpad : -1) : kpad - 25;   // c_0:  [pe_d 39|f2 256]
  else             k = kpad;                                                  // din 256 exact
  int dout = (L == 9) ? 3 : ((L == 10) ? 1 : 256);
  float v = 0.f;
  if (k >= 0 && n < dout) v = wp.p[L][k * dout + n];
  ws[tid] = (_Float16)v;
}

// ---------------------------------------------------------------------------
// One 256-out linear layer; wave cg (0..3) computes rows [0,64) x cols
// [cg*64, cg*64+64). R7: strength-reduced addressing. The swizzled B address
// decomposes as ((u*4+quad)^s7)<<3 == (u^c1)*32 + (quad^(s7&3))*8 with
// c1 = s7>>2, so per K-chunk we pay 1 xor+shift-add for 4 ds_reads (mt is a
// 16-bit immediate), and 1 pointer bump for 4 a-loads (nt is a 1024 B
// immediate). R5 lesson: rolled unroll-2 keeps VGPR~84 (3 waves/SIMD);
// R6 lesson: full unroll costs a resident wave.
// ---------------------------------------------------------------------------
template <int PE_CH, int H_CH, bool RELU>
__device__ __forceinline__ void do_layer(_Float16* lds,
                                         const _Float16* __restrict__ blob,
                                         const float* __restrict__ bias,
                                         int cg, int lane) {
  constexpr int KCH = PE_CH + H_CH;
  const int l15  = lane & 15;
  const int quad = lane >> 4;
  const int s7   = l15 & 7;          // swizzle key (row&7 == l15&7)
  const int c1   = s7 >> 2;          // 0/1: chunk-granule xor bit
  const int q3   = (quad ^ (s7 & 3));

  f32x4 acc[4][4];
#pragma unroll
  for (int mt = 0; mt < 4; ++mt)
#pragma unroll
    for (int nt = 0; nt < 4; ++nt) acc[mt][nt] = (f32x4)0.f;

  half8 a[4], b[4];

  // a-pointer: kcg=0, ntile=cg*4; += 8192 halves per K-chunk
  const _Float16* ap = blob + ((size_t)(cg * 4 * 64 + lane)) * 8;
  const _Float16* pebase = lds + PE_OFF + l15 * 64 + q3 * 8;
  const _Float16* hbase  = lds + H_OFF  + l15 * 256 + q3 * 8;

  // ---- PE segment (<=2 chunks, fully unrolled) ----
#pragma unroll
  for (int kcg = 0; kcg < PE_CH; ++kcg) {
#pragma unroll
    for (int nt = 0; nt < 4; ++nt) a[nt] = *(const half8*)(ap + nt * 512);
    const _Float16* bp = pebase + ((kcg ^ c1) << 5);
#pragma unroll
    for (int mt = 0; mt < 4; ++mt) b[mt] = *(const half8*)(bp + mt * 1024);
#pragma unroll
    for (int mt = 0; mt < 4; ++mt)
#pragma unroll
      for (int nt = 0; nt < 4; ++nt)
        acc[mt][nt] = MFMA_F16(a[nt], b[mt], acc[mt][nt], 0, 0, 0);
    ap += 8192;
  }

  // ---- H segment (rolled, unroll 2; SR addressing) ----
#pragma unroll 2
  for (int u = 0; u < H_CH; ++u) {
#pragma unroll
    for (int nt = 0; nt < 4; ++nt) a[nt] = *(const half8*)(ap + nt * 512);
    const _Float16* bp = hbase + ((u ^ c1) << 5);
#pragma unroll
    for (int mt = 0; mt < 4; ++mt) b[mt] = *(const half8*)(bp + mt * 4096);
#pragma unroll
    for (int mt = 0; mt < 4; ++mt)
#pragma unroll
      for (int nt = 0; nt < 4; ++nt)
        acc[mt][nt] = MFMA_F16(a[nt], b[mt], acc[mt][nt], 0, 0, 0);
    ap += 8192;
  }

  __syncthreads();   // all waves done READING H/PE before anyone overwrites H

  // Epilogue, SR: wa = mt*4096 + l15*256 + cg*64 + t_nt*8 + (quad&1)*4
  // with t_nt = ((nt*2 | (quad>>1)) ^ s7)  (bits disjoint -> OR == ADD).
  const int qb = quad >> 1, q1 = quad & 1;
  _Float16* wbase = lds + H_OFF + l15 * 256 + cg * 64 + q1 * 4;
  _Float16* wp0 = wbase + (((0 | qb) ^ s7) << 3);
  _Float16* wp1 = wbase + (((2 | qb) ^ s7) << 3);
  _Float16* wp2 = wbase + (((4 | qb) ^ s7) << 3);
  _Float16* wp3 = wbase + (((6 | qb) ^ s7) << 3);
  _Float16* wps[4] = {wp0, wp1, wp2, wp3};
#pragma unroll
  for (int mt = 0; mt < 4; ++mt) {
#pragma unroll
    for (int nt = 0; nt < 4; ++nt) {
      int n0 = cg * 64 + nt * 16 + quad * 4;
      f32x4 v = acc[mt][nt];
      f32x4 bb = *(const f32x4*)(bias + n0);
      v += bb;
      if (RELU) {
        v.x = fmaxf(v.x, 0.f); v.y = fmaxf(v.y, 0.f);
        v.z = fmaxf(v.z, 0.f); v.w = fmaxf(v.w, 0.f);
      }
      half4v hv = { (_Float16)v.x, (_Float16)v.y, (_Float16)v.z, (_Float16)v.w };
      *(half4v*)(wps[nt] + mt * 4096) = hv;
    }
  }
  __syncthreads();
}

// Head (sig / c_1): NT=1 blob, K=256 over H; wave w covers rows [w*16,w*16+16).
__device__ __forceinline__ f32x4 head_mt(const _Float16* lds,
                                         const _Float16* __restrict__ blob,
                                         int w, int lane) {
  const int l15  = lane & 15;
  const int quad = lane >> 4;
  const int s7   = l15 & 7;
  const int c1   = s7 >> 2;
  const int q3   = (quad ^ (s7 & 3));
  const _Float16* hb = lds + H_OFF + (w * 16 + l15) * 256 + q3 * 8;
  f32x4 res = (f32x4)0.f;
#pragma unroll
  for (int kc = 0; kc < 8; ++kc) {
    half8 a = *(const half8*)(blob + (kc * 64 + lane) * 8);
    half8 b = *(const half8*)(hb + ((kc ^ c1) << 5));
    res = MFMA_F16(a, b, res, 0, 0, 0);
  }
  return res;
}

// Positional encoding: f = tid&63 is loop-invariant -> classify once per
// thread (R7; was div/mod + branch per element). __sinf/__cosf: abs err
// ~1.5e-4 at |a|<=2560 rad, well under the f16 storage rounding.
__device__ __forceinline__ void pe_pass(_Float16* lds, const float* __restrict__ src,
                                        int row0, int tid, int nfeat) {
  const int f  = tid & 63;
  const int rb = tid >> 6;
  const int fg = f >> 3, f7 = f & 7;
  int mode, c = 0, use_cos = 0;
  float freq = 0.f;
  if (f < 3) { mode = 0; c = f; }
  else if (f < nfeat) {
    int g = f - 3, li = g / 6, rem = g - li * 6;
    use_cos = (rem >= 3); c = use_cos ? rem - 3 : rem;
    freq = (float)(1 << li); mode = 1;
  } else mode = 2;
#pragma unroll
  for (int t = 0; t < 16; ++t) {
    int r = rb + t * 4;
    float v = 0.f;
    if (mode == 0) v = src[(row0 + r) * 3 + c];
    else if (mode == 1) {
      float a = src[(row0 + r) * 3 + c] * freq;
      v = use_cos ? __cosf(a) : __sinf(a);
    }
    lds[PE_OFF + r * 64 + (((fg ^ (r & 7)) << 3) | f7)] = (_Float16)v;
  }
}

__global__ __launch_bounds__(256, 2) void nerf_kernel(
    const _Float16* __restrict__ ws, const float* __restrict__ x,
    const float* __restrict__ dirp, Ptr11 bp, float* __restrict__ out) {
  extern __shared__ _Float16 lds[];
  const int tid  = threadIdx.x;
  const int lane = tid & 63;
  const int w    = tid >> 6;       // wave 0..3 (= col-group cg)
  const int l15  = lane & 15;
  const int quad = lane >> 4;
  const int row0 = blockIdx.x * M_ROWS;

  // ---- pe_x -> PE buffer ----
  pe_pass(lds, x, row0, tid, 63);
  __syncthreads();

  // ---- G1: 63->256, 256->256 x4 (ReLU on all but last) ----
  do_layer<2, 0, true >(lds, ws + OFF_A[0], bp.p[0], w, lane);
  do_layer<0, 8, true >(lds, ws + OFF_A[1], bp.p[1], w, lane);
  do_layer<0, 8, true >(lds, ws + OFF_A[2], bp.p[2], w, lane);
  do_layer<0, 8, true >(lds, ws + OFF_A[3], bp.p[3], w, lane);
  do_layer<0, 8, false>(lds, ws + OFF_A[4], bp.p[4], w, lane);  // f1
  // ---- G2: [pe_x|f1] -> 256, 256->256, 256->256 (no ReLU on last) ----
  do_layer<2, 8, true >(lds, ws + OFF_A[5], bp.p[5], w, lane);  // pe_x last use
  do_layer<0, 8, true >(lds, ws + OFF_A[6], bp.p[6], w, lane);
  do_layer<0, 8, false>(lds, ws + OFF_A[7], bp.p[7], w, lane);  // f2

  // ---- sigma head: wave w covers rows [w*16, w*16+16) (reads f2 in H) ----
  f32x4 sa = head_mt(lds, ws + OFF_A[10], w, lane);
  float sigv = sa[0] + bp.p[10][0];   // valid in quad==0 lanes

  // ---- pe_d recompute into PE buffer (pe_x dead after g2_0) ----
  pe_pass(lds, dirp, row0, tid, 39);
  __syncthreads();   // PE writes visible; sig reads done (barrier covers both)

  // ---- color: [pe_d|f2] -> 256 (ReLU), then 256 -> 3 ----
  do_layer<2, 8, true>(lds, ws + OFF_A[8], bp.p[8], w, lane);
  f32x4 ca = head_mt(lds, ws + OFF_A[9], w, lane);
  if (quad == 0) {
    f32x4 o = { ca[0] + bp.p[9][0], ca[1] + bp.p[9][1], ca[2] + bp.p[9][2], sigv };
    *(f32x4*)(out + (size_t)(row0 + w * 16 + l15) * 4) = o;
  }
}

}  // namespace

extern "C" void kernel_launch(void* const* d_in, const int* in_sizes, int n_in,
                              void* d_out, int out_size, void* d_ws, size_t ws_size,
                              hipStream_t stream) {
  const float* x   = (const float*)d_in[0];
  const float* dir = (const float*)d_in[1];
  Ptr11 wp, bp;
  for (int i = 0; i < 11; ++i) {
    wp.p[i] = (const float*)d_in[2 + 2 * i];
    bp.p[i] = (const float*)d_in[3 + 2 * i];
  }
  _Float16* ws = (_Float16*)d_ws;
  float* out = (float*)d_out;

  hipFuncSetAttribute((const void*)nerf_kernel,
                      hipFuncAttributeMaxDynamicSharedMemorySize, (int)LDS_BYTES);

  prep_kernel<<<TOTAL_W / 256, 256, 0, stream>>>(wp, ws);
  nerf_kernel<<<262144 / M_ROWS, 256, LDS_BYTES, stream>>>(ws, x, dir, bp, out);
}

// Round 8
// 423.387 us; speedup vs baseline: 1.1022x; 1.0455x over previous
//
#include <hip/hip_runtime.h>
#include <hip/hip_fp16.h>
#include <math.h>

typedef _Float16 half8  __attribute__((ext_vector_type(8)));
typedef _Float16 half4v __attribute__((ext_vector_type(4)));
typedef float    f32x4  __attribute__((ext_vector_type(4)));

#define MFMA_F16 __builtin_amdgcn_mfma_f32_16x16x32_f16

namespace {

constexpr int M_ROWS = 128;                  // rows per block (4 waves x 128x64 tile)
// XOR-swizzled packed layouts (granule = 8 halves = 16 B):
//   Haddr(m,n) = m*256 + (((n>>3) ^ (m&7))<<3) + (n&7)     H: 128x256 = 64 KB
//   Paddr(m,k) = PE_OFF + m*64 + (((k>>3) ^ (m&7))<<3) + (k&7)   PE: 16 KB
// 80 KB/block -> exactly 2 blocks/CU by LDS. R8 rationale: MFMA-busy is
// pinned at ~139 us in every R2-R7 variant; wall = stall-bound. 128x64/wave
// doubles MFMA per K-chunk (32 instr, 156 cyc) against the same ~250 cyc L2
// latency exposure -> duty/wave ~38%, x2 waves ~75%.
constexpr int H_OFF      = 0;
constexpr int PE_OFF     = M_ROWS * 256;          // 32768 halves
constexpr int LDS_HALVES = PE_OFF + M_ROWS * 64;  // 40960 halves = 81920 B
constexpr size_t LDS_BYTES = (size_t)LDS_HALVES * sizeof(_Float16);

// Layer order: g1_0..g1_4, g2_0..g2_2, c_0, c_1, sig
constexpr int KCH_A[11] = {2,8,8,8,8,10,8,8,10,8,8};
constexpr int OFF_A[11] = {0,16384,81920,147456,212992,278528,360448,425984,491520,573440,577536};
constexpr int TOTAL_W   = 581632;   // fp16 elements in swizzled blob

struct Ptr11 { const float* p[11]; };

// ---------------------------------------------------------------------------
// Weight pre-swizzle (R7 layout): ntile innermost so the K-loop's 4 a-loads
// share one pointer with 1024 B immediate offsets:
//   256-out layers: blob[((kc*16 + ntile)*64 + lane)*8 + j]
//   heads (L=9,10): blob[(kc*64 + lane)*8 + j]
// Fragment semantics: W[remap(kc*32 + (lane>>4)*8 + j)][ntile*16 + (lane&15)]
// as fp16, 0 if padded (A-frag for mfma_f32_16x16x32_f16).
// ---------------------------------------------------------------------------
__global__ void prep_kernel(Ptr11 wp, _Float16* __restrict__ ws) {
  int tid = blockIdx.x * blockDim.x + threadIdx.x;
  if (tid >= TOTAL_W) return;
  int L = 0;
#pragma unroll
  for (int i = 1; i < 11; ++i) if (tid >= OFF_A[i]) L = i;
  int e    = tid - OFF_A[L];
  int j    = e & 7;
  int lane = (e >> 3) & 63;
  int blk  = e >> 9;
  int kc, nt;
  if (L <= 8) { kc = blk >> 4; nt = blk & 15; }
  else        { kc = blk;      nt = 0; }
  int kpad = kc * 32 + ((lane >> 4) << 3) + j;
  int n    = nt * 16 + (lane & 15);
  int k;
  if      (L == 0) k = (kpad < 63) ? kpad : -1;                               // g1_0: din 63 pad->64
  else if (L == 5) k = (kpad < 64) ? ((kpad < 63) ? kpad : -1) : kpad - 1;    // g2_0: [pe_x 63|f1 256]
  else if (L == 8) k = (kpad < 64) ? ((kpad < 39) ? kpad : -1) : kpad - 25;   // c_0:  [pe_d 39|f2 256]
  else             k = kpad;                                                  // din 256 exact
  int dout = (L == 9) ? 3 : ((L == 10) ? 1 : 256);
  float v = 0.f;
  if (k >= 0 && n < dout) v = wp.p[L][k * dout + n];
  ws[tid] = (_Float16)v;
}

// ---------------------------------------------------------------------------
// One 256-out linear layer; wave cg (0..3) computes rows [0,128) x cols
// [cg*64, cg*64+64). SR addressing (R7): swizzled B address decomposes as
// ((u*4+quad)^s7)<<3 == (u^c1)*32 + (quad^(s7&3))*8, c1 = s7>>2; mt is a
// 16-bit immediate (mt*8192 B), nt a 1024 B immediate off one bumped pointer.
// acc = 8x4 f32x4 = 128 AGPRs; (256,2) cap leaves room -> no spill (R4 rule:
// natural alloc must fit the cap; here ~220 < 256).
// ---------------------------------------------------------------------------
template <int PE_CH, int H_CH, bool RELU>
__device__ __forceinline__ void do_layer(_Float16* lds,
                                         const _Float16* __restrict__ blob,
                                         const float* __restrict__ bias,
                                         int cg, int lane) {
  const int l15  = lane & 15;
  const int quad = lane >> 4;
  const int s7   = l15 & 7;          // swizzle key (row&7 == l15&7)
  const int c1   = s7 >> 2;          // chunk-granule xor bit
  const int q3   = (quad ^ (s7 & 3));

  f32x4 acc[8][4];
#pragma unroll
  for (int mt = 0; mt < 8; ++mt)
#pragma unroll
    for (int nt = 0; nt < 4; ++nt) acc[mt][nt] = (f32x4)0.f;

  half8 a[4], b[8];

  // a-pointer: kcg=0, ntile=cg*4; += 8192 halves per K-chunk
  const _Float16* ap = blob + ((size_t)(cg * 4 * 64 + lane)) * 8;
  const _Float16* pebase = lds + PE_OFF + l15 * 64 + q3 * 8;
  const _Float16* hbase  = lds + H_OFF  + l15 * 256 + q3 * 8;

  // ---- PE segment (<=2 chunks, fully unrolled) ----
#pragma unroll
  for (int kcg = 0; kcg < PE_CH; ++kcg) {
#pragma unroll
    for (int nt = 0; nt < 4; ++nt) a[nt] = *(const half8*)(ap + nt * 512);
    const _Float16* bp = pebase + ((kcg ^ c1) << 5);
#pragma unroll
    for (int mt = 0; mt < 8; ++mt) b[mt] = *(const half8*)(bp + mt * 1024);
#pragma unroll
    for (int mt = 0; mt < 8; ++mt)
#pragma unroll
      for (int nt = 0; nt < 4; ++nt)
        acc[mt][nt] = MFMA_F16(a[nt], b[mt], acc[mt][nt], 0, 0, 0);
    ap += 8192;
  }

  // ---- H segment (rolled, unroll 2; SR addressing) ----
#pragma unroll 2
  for (int u = 0; u < H_CH; ++u) {
#pragma unroll
    for (int nt = 0; nt < 4; ++nt) a[nt] = *(const half8*)(ap + nt * 512);
    const _Float16* bp = hbase + ((u ^ c1) << 5);
#pragma unroll
    for (int mt = 0; mt < 8; ++mt) b[mt] = *(const half8*)(bp + mt * 4096);
#pragma unroll
    for (int mt = 0; mt < 8; ++mt)
#pragma unroll
      for (int nt = 0; nt < 4; ++nt)
        acc[mt][nt] = MFMA_F16(a[nt], b[mt], acc[mt][nt], 0, 0, 0);
    ap += 8192;
  }

  __syncthreads();   // all waves done READING H/PE before anyone overwrites H

  // Epilogue, SR: wa = mt*4096 + l15*256 + cg*64 + ((nt*2|qb)^s7)*8 + q1*4
  const int qb = quad >> 1, q1 = quad & 1;
  _Float16* wbase = lds + H_OFF + l15 * 256 + cg * 64 + q1 * 4;
  _Float16* wps[4] = { wbase + (((0 | qb) ^ s7) << 3),
                       wbase + (((2 | qb) ^ s7) << 3),
                       wbase + (((4 | qb) ^ s7) << 3),
                       wbase + (((6 | qb) ^ s7) << 3) };
#pragma unroll
  for (int mt = 0; mt < 8; ++mt) {
#pragma unroll
    for (int nt = 0; nt < 4; ++nt) {
      int n0 = cg * 64 + nt * 16 + quad * 4;
      f32x4 v = acc[mt][nt];
      f32x4 bb = *(const f32x4*)(bias + n0);
      v += bb;
      if (RELU) {
        v.x = fmaxf(v.x, 0.f); v.y = fmaxf(v.y, 0.f);
        v.z = fmaxf(v.z, 0.f); v.w = fmaxf(v.w, 0.f);
      }
      half4v hv = { (_Float16)v.x, (_Float16)v.y, (_Float16)v.z, (_Float16)v.w };
      *(half4v*)(wps[nt] + mt * 4096) = hv;
    }
  }
  __syncthreads();
}

// Head (sig / c_1): NT=1 blob, K=256 over H for one 16-row group at r0.
__device__ __forceinline__ f32x4 head_mt(const _Float16* lds,
                                         const _Float16* __restrict__ blob,
                                         int r0, int lane) {
  const int l15  = lane & 15;
  const int quad = lane >> 4;
  const int s7   = l15 & 7;
  const int c1   = s7 >> 2;
  const int q3   = (quad ^ (s7 & 3));
  const _Float16* hb = lds + H_OFF + (r0 + l15) * 256 + q3 * 8;
  f32x4 res = (f32x4)0.f;
#pragma unroll
  for (int kc = 0; kc < 8; ++kc) {
    half8 a = *(const half8*)(blob + (kc * 64 + lane) * 8);
    half8 b = *(const half8*)(hb + ((kc ^ c1) << 5));
    res = MFMA_F16(a, b, res, 0, 0, 0);
  }
  return res;
}

// Positional encoding: f = tid&63 loop-invariant -> classify once per thread.
// __sinf/__cosf: abs err ~1.5e-4, well under the f16 storage rounding.
__device__ __forceinline__ void pe_pass(_Float16* lds, const float* __restrict__ src,
                                        int row0, int tid, int nfeat) {
  const int f  = tid & 63;
  const int rb = tid >> 6;
  const int fg = f >> 3, f7 = f & 7;
  int mode, c = 0, use_cos = 0;
  float freq = 0.f;
  if (f < 3) { mode = 0; c = f; }
  else if (f < nfeat) {
    int g = f - 3, li = g / 6, rem = g - li * 6;
    use_cos = (rem >= 3); c = use_cos ? rem - 3 : rem;
    freq = (float)(1 << li); mode = 1;
  } else mode = 2;
  for (int t = 0; t < 32; ++t) {
    int r = rb + t * 4;
    float v = 0.f;
    if (mode == 0) v = src[(row0 + r) * 3 + c];
    else if (mode == 1) {
      float a = src[(row0 + r) * 3 + c] * freq;
      v = use_cos ? __cosf(a) : __sinf(a);
    }
    lds[PE_OFF + r * 64 + (((fg ^ (r & 7)) << 3) | f7)] = (_Float16)v;
  }
}

__global__ __launch_bounds__(256, 2) void nerf_kernel(
    const _Float16* __restrict__ ws, const float* __restrict__ x,
    const float* __restrict__ dirp, Ptr11 bp, float* __restrict__ out) {
  extern __shared__ _Float16 lds[];
  const int tid  = threadIdx.x;
  const int lane = tid & 63;
  const int w    = tid >> 6;       // wave 0..3 (= col-group cg)
  const int l15  = lane & 15;
  const int quad = lane >> 4;
  const int row0 = blockIdx.x * M_ROWS;

  // ---- pe_x -> PE buffer ----
  pe_pass(lds, x, row0, tid, 63);
  __syncthreads();

  // ---- G1: 63->256, 256->256 x4 (ReLU on all but last) ----
  do_layer<2, 0, true >(lds, ws + OFF_A[0], bp.p[0], w, lane);
  do_layer<0, 8, true >(lds, ws + OFF_A[1], bp.p[1], w, lane);
  do_layer<0, 8, true >(lds, ws + OFF_A[2], bp.p[2], w, lane);
  do_layer<0, 8, true >(lds, ws + OFF_A[3], bp.p[3], w, lane);
  do_layer<0, 8, false>(lds, ws + OFF_A[4], bp.p[4], w, lane);  // f1
  // ---- G2: [pe_x|f1] -> 256, 256->256, 256->256 (no ReLU on last) ----
  do_layer<2, 8, true >(lds, ws + OFF_A[5], bp.p[5], w, lane);  // pe_x last use
  do_layer<0, 8, true >(lds, ws + OFF_A[6], bp.p[6], w, lane);
  do_layer<0, 8, false>(lds, ws + OFF_A[7], bp.p[7], w, lane);  // f2

  // ---- sigma head: wave w covers rows [w*32, w*32+32) (reads f2 in H) ----
  f32x4 sa0 = head_mt(lds, ws + OFF_A[10], w * 32,      lane);
  f32x4 sa1 = head_mt(lds, ws + OFF_A[10], w * 32 + 16, lane);
  float sig0 = sa0[0] + bp.p[10][0];   // valid in quad==0 lanes
  float sig1 = sa1[0] + bp.p[10][0];

  // ---- pe_d recompute into PE buffer (pe_x dead after g2_0) ----
  pe_pass(lds, dirp, row0, tid, 39);
  __syncthreads();   // PE writes visible; sig reads done (barrier covers both)

  // ---- color: [pe_d|f2] -> 256 (ReLU), then 256 -> 3 ----
  do_layer<2, 8, true>(lds, ws + OFF_A[8], bp.p[8], w, lane);
  f32x4 ca0 = head_mt(lds, ws + OFF_A[9], w * 32,      lane);
  f32x4 ca1 = head_mt(lds, ws + OFF_A[9], w * 32 + 16, lane);
  if (quad == 0) {
    float b0 = bp.p[9][0], b1 = bp.p[9][1], b2 = bp.p[9][2];
    f32x4 o0 = { ca0[0] + b0, ca0[1] + b1, ca0[2] + b2, sig0 };
    f32x4 o1 = { ca1[0] + b0, ca1[1] + b1, ca1[2] + b2, sig1 };
    *(f32x4*)(out + (size_t)(row0 + w * 32 + l15) * 4) = o0;
    *(f32x4*)(out + (size_t)(row0 + w * 32 + 16 + l15) * 4) = o1;
  }
}

}  // namespace

extern "C" void kernel_launch(void* const* d_in, const int* in_sizes, int n_in,
                              void* d_out, int out_size, void* d_ws, size_t ws_size,
                              hipStream_t stream) {
  const float* x   = (const float*)d_in[0];
  const float* dir = (const float*)d_in[1];
  Ptr11 wp, bp;
  for (int i = 0; i < 11; ++i) {
    wp.p[i] = (const float*)d_in[2 + 2 * i];
    bp.p[i] = (const float*)d_in[3 + 2 * i];
  }
  _Float16* ws = (_Float16*)d_ws;
  float* out = (float*)d_out;

  hipFuncSetAttribute((const void*)nerf_kernel,
                      hipFuncAttributeMaxDynamicSharedMemorySize, (int)LDS_BYTES);

  prep_kernel<<<TOTAL_W / 256, 256, 0, stream>>>(wp, ws);
  nerf_kernel<<<262144 / M_ROWS, 256, LDS_BYTES, stream>>>(ws, x, dir, bp, out);
}